// Round 2
// baseline (723.225 us; speedup 1.0000x reference)
//
#include <hip/hip_runtime.h>

// R2: barrier-free per-wave gauss stack + fused dense0/dense1 epilogue.
// - 1 block = 4 waves = 4 samples; each wave owns a 16KB LDS region
//   (8KB ping + 8KB pong, XOR-swizzled 16B chunks, no padding).
// - Gauss stack has ZERO __syncthreads (per-wave LDS only; compiler lgkmcnt).
//   Stage A: xp^T[o][h] = (act_R @ w^T)^T via MFMA A=act_R, B=w  (C-layout
//   stores f16x4-contiguous into xp^T). Stage B: A=xp^T, B=K~ (row-major!)
//   gives D[m=o][n=i] whose C-layout stores f16x4-contiguous into act_R[i][o].
//   Zero-padded w columns kill stale act columns -> no LDS zeroing needed.
// - 3 barriers/block total (was 57): before dense0 (cross-wave h reads),
//   after partials, after h1.
// - LDS 65536 B -> 2 blocks/CU; waves fully independent during gauss.

typedef _Float16 f16x8 __attribute__((ext_vector_type(8)));
typedef _Float16 f16x4 __attribute__((ext_vector_type(4)));
typedef float    f32x4 __attribute__((ext_vector_type(4)));

// ws layout (halves): [0] wm0 fp16 [80][4096]; K~ [4][64][64]; padded weights
#define KT_OFF    327680
#define W0P_OFF   344064               // [16][64], rows>=8 zero
#define W1P_OFF   345088               // [16][32], cols>=8 zero
#define W2P_OFF   345600               // [32][32], cols>=16 zero
#define W3P_OFF   346624               // [64][32]

__global__ void prep_k_kernel(const float* __restrict__ s0, const float* __restrict__ s1,
                              const float* __restrict__ s2, const float* __restrict__ s3,
                              _Float16* __restrict__ kt) {
  int r = threadIdx.x;                 // 256 threads: (layer, row)
  int li = r >> 6, i = r & 63;
  float sg = (li == 0) ? s0[0] : (li == 1) ? s1[0] : (li == 2) ? s2[0] : s3[0];
  float denom = 2.0f * sg * sg;
  float sum = 0.0f;
  for (int j = 0; j < 64; ++j) {
    float d = (float)(i - j);
    sum += expf(-(d * d) / denom);
  }
  float inv = 1.0f / fmaxf(sum, 1e-12f);
  for (int j = 0; j < 64; ++j) {
    float d = (float)(i - j);
    kt[(li * 64 + i) * 64 + j] = (_Float16)(expf(-(d * d) / denom) * inv);
  }
}

__global__ void prep_w_kernel(const float* __restrict__ w0, const float* __restrict__ w1,
                              const float* __restrict__ w2, const float* __restrict__ w3,
                              const float* __restrict__ wm0, _Float16* __restrict__ base) {
  int idx = blockIdx.x * 256 + threadIdx.x;
  if (idx >= 332288) return;
  if (idx < 327680) { base[idx] = (_Float16)wm0[idx]; return; }
  int r = idx - 327680;
  float v;
  if (r < 1024)      { int o = r >> 6, c = r & 63;             v = (o < 8)  ? w0[o * 64 + c] : 0.0f; }
  else if (r < 1536) { int q = r - 1024; int o = q >> 5, c = q & 31; v = (c < 8)  ? w1[o * 8 + c]  : 0.0f; }
  else if (r < 2560) { int q = r - 1536; int o = q >> 5, c = q & 31; v = (c < 16) ? w2[o * 16 + c] : 0.0f; }
  else               { int q = r - 2560; int o = q >> 5, c = q & 31; v = w3[o * 32 + c]; }
  base[344064 + r] = (_Float16)v;
}

__device__ __forceinline__ float leaky(float v) { return v > 0.0f ? v : 0.01f * v; }

// swizzled offset (halves) within an 8KB 64x64 fp16 buffer: 16B chunk j -> j ^ (row&7)
__device__ __forceinline__ int swz(int row, int c) {
  return row * 64 + ((((c >> 3) ^ (row & 7))) << 3) + (c & 7);
}

// stage A: xpT[o][h] from act_R[h][c] and w[o][c] (KPAD row stride, zero-padded)
template<int NT, int KC, int KPAD>
__device__ __forceinline__ void stage_a(const _Float16* __restrict__ src, _Float16* __restrict__ dst,
                                        const _Float16* __restrict__ wp, const float* bv,
                                        int lo, int hi) {
  f16x8 a[4][KC];
#pragma unroll
  for (int mt = 0; mt < 4; ++mt)
#pragma unroll
    for (int kc = 0; kc < KC; ++kc)
      a[mt][kc] = *(const f16x8*)(src + swz(mt * 16 + lo, kc * 32 + hi * 8));
  f16x8 wf[NT][KC];
#pragma unroll
  for (int nt = 0; nt < NT; ++nt)
#pragma unroll
    for (int kc = 0; kc < KC; ++kc)
      wf[nt][kc] = *(const f16x8*)(wp + (nt * 16 + lo) * KPAD + kc * 32 + hi * 8);
#pragma unroll
  for (int mt = 0; mt < 4; ++mt)
#pragma unroll
    for (int nt = 0; nt < NT; ++nt) {
      f32x4 acc = {0.0f, 0.0f, 0.0f, 0.0f};
#pragma unroll
      for (int kc = 0; kc < KC; ++kc)
        acc = __builtin_amdgcn_mfma_f32_16x16x32_f16(a[mt][kc], wf[nt][kc], acc, 0, 0, 0);
      // D[m=h=mt*16+hi*4+r][n=o=nt*16+lo] -> xpT[o][h..h+3]
      f16x4 hv;
#pragma unroll
      for (int r = 0; r < 4; ++r) hv[r] = (_Float16)(acc[r] + bv[nt]);
      *(f16x4*)(dst + swz(nt * 16 + lo, mt * 16 + hi * 4)) = hv;
    }
}

// stage B: act_R[i][o] = leaky( sum_j K~[i][j] * xpT[o][j] ), MT = Cout/16
template<int MT>
__device__ __forceinline__ void stage_b(const _Float16* __restrict__ xp, _Float16* __restrict__ act,
                                        const _Float16* __restrict__ kmat, int lo, int hi) {
  f16x8 ax[MT][2];
#pragma unroll
  for (int ot = 0; ot < MT; ++ot)
#pragma unroll
    for (int kc = 0; kc < 2; ++kc)
      ax[ot][kc] = *(const f16x8*)(xp + swz(ot * 16 + lo, kc * 32 + hi * 8));
  f16x8 kb[4][2];
#pragma unroll
  for (int nt = 0; nt < 4; ++nt)
#pragma unroll
    for (int kc = 0; kc < 2; ++kc)
      kb[nt][kc] = *(const f16x8*)(kmat + (nt * 16 + lo) * 64 + kc * 32 + hi * 8);
#pragma unroll
  for (int ot = 0; ot < MT; ++ot)
#pragma unroll
    for (int nt = 0; nt < 4; ++nt) {
      f32x4 acc = {0.0f, 0.0f, 0.0f, 0.0f};
#pragma unroll
      for (int kc = 0; kc < 2; ++kc)
        acc = __builtin_amdgcn_mfma_f32_16x16x32_f16(ax[ot][kc], kb[nt][kc], acc, 0, 0, 0);
      // D[m=o=ot*16+hi*4+r][n=i=nt*16+lo] -> act_R[i][o..o+3]
      f16x4 hv;
#pragma unroll
      for (int r = 0; r < 4; ++r) hv[r] = (_Float16)leaky(acc[r]);
      *(f16x4*)(act + swz(nt * 16 + lo, ot * 16 + hi * 4)) = hv;
    }
}

__global__ __launch_bounds__(256, 2)
void gauss_main(const float* __restrict__ x,
                const float* __restrict__ bb0, const float* __restrict__ bb1,
                const float* __restrict__ bb2, const float* __restrict__ bb3,
                const float* __restrict__ bm0, const float* __restrict__ wm1,
                const float* __restrict__ bm1,
                const _Float16* __restrict__ wsh,
                float* __restrict__ out, int B) {
  extern __shared__ char smem[];
  _Float16* lds = (_Float16*)smem;
  const int tid = threadIdx.x;
  const int wv = tid >> 6, lane = tid & 63;
  const int lo = lane & 15, hi = lane >> 4;
  const int b0s = blockIdx.x * 4;
  const int smp = b0s + wv;

  _Float16* P = lds + wv * 8192;        // act buffer (8KB)
  _Float16* Q = P + 4096;               // xpT scratch (8KB)

  // per-lane biases
  float bv0 = (lo < 8) ? bb0[lo] : 0.0f;
  float bv1 = bb1[lo];
  float bv2[2] = {bb2[lo], bb2[16 + lo]};
  float bv3[4] = {bb3[lo], bb3[16 + lo], bb3[32 + lo], bb3[48 + lo]};

  // ---- x -> act_R (fp16, swizzled), fully per-wave ----
  if (smp < B) {
    const float4* xv = (const float4*)(x + (size_t)smp * 4096);
#pragma unroll
    for (int t = 0; t < 16; ++t) {
      float4 v = xv[t * 64 + lane];
      f16x4 hv;
      hv[0] = (_Float16)v.x; hv[1] = (_Float16)v.y; hv[2] = (_Float16)v.z; hv[3] = (_Float16)v.w;
      *(f16x4*)(P + swz(t * 4 + hi, lo * 4)) = hv;
    }
  }

  // ---- gauss stack: zero barriers ----
  const _Float16* kt = wsh + KT_OFF;
  stage_a<1, 2, 64>(P, Q, wsh + W0P_OFF, &bv0, lo, hi);
  stage_b<1>(Q, P, kt + 0 * 4096, lo, hi);
  stage_a<1, 1, 32>(P, Q, wsh + W1P_OFF, &bv1, lo, hi);
  stage_b<1>(Q, P, kt + 1 * 4096, lo, hi);
  stage_a<2, 1, 32>(P, Q, wsh + W2P_OFF, bv2, lo, hi);
  stage_b<2>(Q, P, kt + 2 * 4096, lo, hi);
  stage_a<4, 1, 32>(P, Q, wsh + W3P_OFF, bv3, lo, hi);
  stage_b<4>(Q, P, kt + 3 * 4096, lo, hi);

  __syncthreads();   // h (act_R) of all 4 samples now visible block-wide

  // ---- dense0: C[s][n] = h[s][:4096] . wm0[n][:4096]; 4-way K-split ----
  f32x4 dacc[5];
#pragma unroll
  for (int nt = 0; nt < 5; ++nt) { f32x4 z = {0.0f, 0.0f, 0.0f, 0.0f}; dacc[nt] = z; }
  const int kbase = wv * 1024;
  for (int ks = 0; ks < 32; ++ks) {
    int k = kbase + ks * 32 + hi * 8;
    f16x8 a = {};
    if (lo < 4) {
      int row = k >> 6, c = k & 63;
      a = *(const f16x8*)(lds + lo * 8192 + swz(row, c));
    }
#pragma unroll
    for (int nt = 0; nt < 5; ++nt) {
      f16x8 b = *(const f16x8*)(wsh + (size_t)(nt * 16 + lo) * 4096 + k);
      dacc[nt] = __builtin_amdgcn_mfma_f32_16x16x32_f16(a, b, dacc[nt], 0, 0, 0);
    }
  }
  // partial C rows 0..3 (samples) -> wave's Q region as f32 [4][80]
  float* part = (float*)(smem + wv * 16384 + 8192);
  if (hi == 0) {
#pragma unroll
    for (int nt = 0; nt < 5; ++nt)
#pragma unroll
      for (int r = 0; r < 4; ++r)
        part[r * 80 + nt * 16 + lo] = dacc[nt][r];
  }
  __syncthreads();

  // ---- reduce 4 wave-partials + bias + leaky -> h1 [4][80] f32 ----
  float* h1 = (float*)(smem + 8192 + 1280);
  for (int e = tid; e < 4 * 80; e += 256) {
    int ss = e / 80, n = e - ss * 80;
    float v = bm0[n];
#pragma unroll
    for (int w = 0; w < 4; ++w) v += ((const float*)(smem + w * 16384 + 8192))[ss * 80 + n];
    h1[e] = leaky(v);
  }
  __syncthreads();

  // ---- dense1 fp32 VALU + store ----
  for (int e = tid; e < 4 * 60; e += 256) {
    int ss = e / 60, n = e - ss * 60;
    float v = bm1[n];
    const float4* hr = (const float4*)(h1 + ss * 80);
    const float4* wr = (const float4*)(wm1 + n * 80);
#pragma unroll
    for (int k2 = 0; k2 < 20; ++k2) {
      float4 hv = hr[k2], wv4 = wr[k2];
      v += hv.x * wv4.x + hv.y * wv4.y + hv.z * wv4.z + hv.w * wv4.w;
    }
    int s2 = b0s + ss;
    if (s2 < B) out[(size_t)s2 * 60 + n] = leaky(v);
  }
}

extern "C" void kernel_launch(void* const* d_in, const int* in_sizes, int n_in,
                              void* d_out, int out_size, void* d_ws, size_t ws_size,
                              hipStream_t stream) {
  const float* x   = (const float*)d_in[0];
  const float* w0  = (const float*)d_in[1];
  const float* b0  = (const float*)d_in[2];
  const float* s0  = (const float*)d_in[3];
  const float* w1  = (const float*)d_in[4];
  const float* b1  = (const float*)d_in[5];
  const float* s1  = (const float*)d_in[6];
  const float* w2  = (const float*)d_in[7];
  const float* b2  = (const float*)d_in[8];
  const float* s2  = (const float*)d_in[9];
  const float* w3  = (const float*)d_in[10];
  const float* b3  = (const float*)d_in[11];
  const float* s3  = (const float*)d_in[12];
  const float* wm0 = (const float*)d_in[13];
  const float* bm0 = (const float*)d_in[14];
  const float* wm1 = (const float*)d_in[15];
  const float* bm1 = (const float*)d_in[16];
  float* out = (float*)d_out;
  _Float16* wsh = (_Float16*)d_ws;

  int B = in_sizes[0] / 4096;
  prep_k_kernel<<<1, 256, 0, stream>>>(s0, s1, s2, s3, wsh + KT_OFF);
  prep_w_kernel<<<1298, 256, 0, stream>>>(w0, w1, w2, w3, wm0, wsh);
  int blocks = (B + 3) / 4;
  gauss_main<<<blocks, 256, 65536, stream>>>(x, b0, b1, b2, b3, bm0, wm1, bm1, wsh, out, B);
}

// Round 3
// 539.517 us; speedup vs baseline: 1.3405x; 1.3405x over previous
//
#include <hip/hip_runtime.h>

// R3: two-phase split.
// gauss_phase: per-wave barrier-free MFMA gauss stack, single 8KB in-place
//   LDS buffer per wave (all fragments register-loaded before stores; per-wave
//   DS FIFO ordering => safe). 32KB/block -> 5 blocks/CU. Writes h fp16 to
//   scratch (d_ws if large enough, else over the sample's own consumed x).
// dense_phase: dense0 as GEMM, block=16 samples, 4 waves K-split 4x1024,
//   wm0-fp16 read once per block (16x less L2 traffic than R2), LDS reduce,
//   fp32 dense1. Both kernels high-occupancy, short dependency chains.

typedef _Float16 f16x8 __attribute__((ext_vector_type(8)));
typedef _Float16 f16x4 __attribute__((ext_vector_type(4)));
typedef float    f32x4 __attribute__((ext_vector_type(4)));

// ws layout (halves): [0] wm0 fp16 [80][4096]; K~ [4][64][64]; padded weights
#define KT_OFF    327680
#define W0P_OFF   344064               // [16][64], rows>=8 zero
#define W1P_OFF   345088               // [16][32], cols>=8 zero
#define W2P_OFF   345600               // [32][32], cols>=16 zero
#define W3P_OFF   346624               // [64][32]
#define H_BYTE_OFF 1048576             // h buffer at +1MB when ws is big enough

__global__ void prep_k_kernel(const float* __restrict__ s0, const float* __restrict__ s1,
                              const float* __restrict__ s2, const float* __restrict__ s3,
                              _Float16* __restrict__ kt) {
  int r = threadIdx.x;
  int li = r >> 6, i = r & 63;
  float sg = (li == 0) ? s0[0] : (li == 1) ? s1[0] : (li == 2) ? s2[0] : s3[0];
  float denom = 2.0f * sg * sg;
  float sum = 0.0f;
  for (int j = 0; j < 64; ++j) {
    float d = (float)(i - j);
    sum += expf(-(d * d) / denom);
  }
  float inv = 1.0f / fmaxf(sum, 1e-12f);
  for (int j = 0; j < 64; ++j) {
    float d = (float)(i - j);
    kt[(li * 64 + i) * 64 + j] = (_Float16)(expf(-(d * d) / denom) * inv);
  }
}

__global__ void prep_w_kernel(const float* __restrict__ w0, const float* __restrict__ w1,
                              const float* __restrict__ w2, const float* __restrict__ w3,
                              const float* __restrict__ wm0, _Float16* __restrict__ base) {
  int idx = blockIdx.x * 256 + threadIdx.x;
  if (idx >= 332288) return;
  if (idx < 327680) { base[idx] = (_Float16)wm0[idx]; return; }
  int r = idx - 327680;
  float v;
  if (r < 1024)      { int o = r >> 6, c = r & 63;             v = (o < 8)  ? w0[o * 64 + c] : 0.0f; }
  else if (r < 1536) { int q = r - 1024; int o = q >> 5, c = q & 31; v = (c < 8)  ? w1[o * 8 + c]  : 0.0f; }
  else if (r < 2560) { int q = r - 1536; int o = q >> 5, c = q & 31; v = (c < 16) ? w2[o * 16 + c] : 0.0f; }
  else               { int q = r - 2560; int o = q >> 5, c = q & 31; v = w3[o * 32 + c]; }
  base[344064 + r] = (_Float16)v;
}

__device__ __forceinline__ float leaky(float v) { return v > 0.0f ? v : 0.01f * v; }

// swizzled offset (halves) in an 8KB 64x64 fp16 buffer: 16B chunk j -> j ^ (row&7)
__device__ __forceinline__ int swz(int row, int c) {
  return row * 64 + ((((c >> 3) ^ (row & 7))) << 3) + (c & 7);
}

// stage A (in-place): xpT[o][h] over P from act_R[h][c] in P and w[o][c].
// All P-reads complete into registers before any P-store.
template<int NT, int KC, int KPAD>
__device__ __forceinline__ void stage_a(_Float16* __restrict__ P,
                                        const _Float16* __restrict__ wp, const float* bv,
                                        int lo, int hi) {
  f16x8 a[4][KC];
#pragma unroll
  for (int mt = 0; mt < 4; ++mt)
#pragma unroll
    for (int kc = 0; kc < KC; ++kc)
      a[mt][kc] = *(const f16x8*)(P + swz(mt * 16 + lo, kc * 32 + hi * 8));
  f16x8 wf[NT][KC];
#pragma unroll
  for (int nt = 0; nt < NT; ++nt)
#pragma unroll
    for (int kc = 0; kc < KC; ++kc)
      wf[nt][kc] = *(const f16x8*)(wp + (nt * 16 + lo) * KPAD + kc * 32 + hi * 8);
#pragma unroll
  for (int mt = 0; mt < 4; ++mt)
#pragma unroll
    for (int nt = 0; nt < NT; ++nt) {
      f32x4 acc = {0.0f, 0.0f, 0.0f, 0.0f};
#pragma unroll
      for (int kc = 0; kc < KC; ++kc)
        acc = __builtin_amdgcn_mfma_f32_16x16x32_f16(a[mt][kc], wf[nt][kc], acc, 0, 0, 0);
      f16x4 hv;
#pragma unroll
      for (int r = 0; r < 4; ++r) hv[r] = (_Float16)(acc[r] + bv[nt]);
      *(f16x4*)(P + swz(nt * 16 + lo, mt * 16 + hi * 4)) = hv;
    }
}

// stage B (in-place): act_R[i][o] = leaky(sum_j K~[i][j] * xpT[o][j])
template<int MT>
__device__ __forceinline__ void stage_b(_Float16* __restrict__ P,
                                        const _Float16* __restrict__ kmat, int lo, int hi) {
  f16x8 ax[MT][2];
#pragma unroll
  for (int ot = 0; ot < MT; ++ot)
#pragma unroll
    for (int kc = 0; kc < 2; ++kc)
      ax[ot][kc] = *(const f16x8*)(P + swz(ot * 16 + lo, kc * 32 + hi * 8));
  f16x8 kb[4][2];
#pragma unroll
  for (int nt = 0; nt < 4; ++nt)
#pragma unroll
    for (int kc = 0; kc < 2; ++kc)
      kb[nt][kc] = *(const f16x8*)(kmat + (nt * 16 + lo) * 64 + kc * 32 + hi * 8);
#pragma unroll
  for (int ot = 0; ot < MT; ++ot)
#pragma unroll
    for (int nt = 0; nt < 4; ++nt) {
      f32x4 acc = {0.0f, 0.0f, 0.0f, 0.0f};
#pragma unroll
      for (int kc = 0; kc < 2; ++kc)
        acc = __builtin_amdgcn_mfma_f32_16x16x32_f16(ax[ot][kc], kb[nt][kc], acc, 0, 0, 0);
      f16x4 hv;
#pragma unroll
      for (int r = 0; r < 4; ++r) hv[r] = (_Float16)leaky(acc[r]);
      *(f16x4*)(P + swz(nt * 16 + lo, ot * 16 + hi * 4)) = hv;
    }
}

__global__ __launch_bounds__(256, 4)
void gauss_phase(const float* __restrict__ x, _Float16* __restrict__ hout,
                 const float* __restrict__ bb0, const float* __restrict__ bb1,
                 const float* __restrict__ bb2, const float* __restrict__ bb3,
                 const _Float16* __restrict__ wsh, int B) {
  __shared__ _Float16 lds[4][4096];   // 32KB -> 5 blocks/CU
  const int tid = threadIdx.x;
  const int wv = tid >> 6, lane = tid & 63;
  const int lo = lane & 15, hi = lane >> 4;
  const int smp = blockIdx.x * 4 + wv;
  if (smp >= B) return;               // whole-wave exit; kernel has no barriers
  _Float16* P = lds[wv];

  float bv0 = (lo < 8) ? bb0[lo] : 0.0f;
  float bv1 = bb1[lo];
  float bv2[2] = {bb2[lo], bb2[16 + lo]};
  float bv3[4] = {bb3[lo], bb3[16 + lo], bb3[32 + lo], bb3[48 + lo]};

  // x -> act_R fp16 swizzled (1KB contiguous per instruction)
  const float4* xv = (const float4*)(x + (size_t)smp * 4096);
#pragma unroll
  for (int t = 0; t < 16; ++t) {
    float4 v = xv[t * 64 + lane];
    f16x4 hv;
    hv[0] = (_Float16)v.x; hv[1] = (_Float16)v.y; hv[2] = (_Float16)v.z; hv[3] = (_Float16)v.w;
    *(f16x4*)(P + swz(t * 4 + hi, lo * 4)) = hv;
  }

  const _Float16* kt = wsh + KT_OFF;
  stage_a<1, 2, 64>(P, wsh + W0P_OFF, &bv0, lo, hi);
  stage_b<1>(P, kt + 0 * 4096, lo, hi);
  stage_a<1, 1, 32>(P, wsh + W1P_OFF, &bv1, lo, hi);
  stage_b<1>(P, kt + 1 * 4096, lo, hi);
  stage_a<2, 1, 32>(P, wsh + W2P_OFF, bv2, lo, hi);
  stage_b<2>(P, kt + 2 * 4096, lo, hi);
  stage_a<4, 1, 32>(P, wsh + W3P_OFF, bv3, lo, hi);
  stage_b<4>(P, kt + 3 * 4096, lo, hi);

  // h (act_R) -> global, de-swizzled, 1KB contiguous per instruction
  _Float16* g = hout + (size_t)smp * 4096;
#pragma unroll
  for (int t = 0; t < 8; ++t) {
    int c = t * 64 + lane;
    int i = c >> 3, j = c & 7;
    f16x8 v = *(const f16x8*)(P + i * 64 + ((j ^ (i & 7)) << 3));
    *(f16x8*)(g + (size_t)c * 8) = v;
  }
}

__global__ __launch_bounds__(256, 4)
void dense_phase(const _Float16* __restrict__ h, const _Float16* __restrict__ wm0f,
                 const float* __restrict__ bm0, const float* __restrict__ wm1,
                 const float* __restrict__ bm1, float* __restrict__ out, int B) {
  __shared__ float part[4][16][84];   // pad 84: kills 4-way bank conflict
  __shared__ float h1[16][84];
  const int tid = threadIdx.x;
  const int wv = tid >> 6, lane = tid & 63;
  const int lo = lane & 15, hi = lane >> 4;
  const int m0 = blockIdx.x * 16;

  int row = m0 + lo;
  if (row >= B) row = B - 1;          // clamp; OOB outputs masked at store
  const _Float16* abase = h + (size_t)row * 4096 + wv * 1024 + hi * 8;

  f32x4 acc[5];
#pragma unroll
  for (int nt = 0; nt < 5; ++nt) { f32x4 z = {0.0f, 0.0f, 0.0f, 0.0f}; acc[nt] = z; }

  for (int it = 0; it < 32; ++it) {
    f16x8 a = *(const f16x8*)(abase + it * 32);
    int kk = wv * 1024 + it * 32 + hi * 8;
#pragma unroll
    for (int nt = 0; nt < 5; ++nt) {
      f16x8 b = *(const f16x8*)(wm0f + (size_t)(nt * 16 + lo) * 4096 + kk);
      acc[nt] = __builtin_amdgcn_mfma_f32_16x16x32_f16(a, b, acc[nt], 0, 0, 0);
    }
  }
#pragma unroll
  for (int nt = 0; nt < 5; ++nt)
#pragma unroll
    for (int r = 0; r < 4; ++r)
      part[wv][hi * 4 + r][nt * 16 + lo] = acc[nt][r];
  __syncthreads();

  for (int e = tid; e < 16 * 80; e += 256) {
    int m = e / 80, n = e - m * 80;
    float v = bm0[n] + part[0][m][n] + part[1][m][n] + part[2][m][n] + part[3][m][n];
    h1[m][n] = leaky(v);
  }
  __syncthreads();

  for (int e = tid; e < 16 * 60; e += 256) {
    int m = e / 60, n = e - m * 60;
    float v = bm1[n];
    const float4* hr = (const float4*)&h1[m][0];
    const float4* wr = (const float4*)(wm1 + n * 80);
#pragma unroll
    for (int k2 = 0; k2 < 20; ++k2) {
      float4 hv = hr[k2], wv4 = wr[k2];
      v += hv.x * wv4.x + hv.y * wv4.y + hv.z * wv4.z + hv.w * wv4.w;
    }
    int s = m0 + m;
    if (s < B) out[(size_t)s * 60 + n] = leaky(v);
  }
}

extern "C" void kernel_launch(void* const* d_in, const int* in_sizes, int n_in,
                              void* d_out, int out_size, void* d_ws, size_t ws_size,
                              hipStream_t stream) {
  const float* x   = (const float*)d_in[0];
  const float* w0  = (const float*)d_in[1];
  const float* b0  = (const float*)d_in[2];
  const float* s0  = (const float*)d_in[3];
  const float* w1  = (const float*)d_in[4];
  const float* b1  = (const float*)d_in[5];
  const float* s1  = (const float*)d_in[6];
  const float* w2  = (const float*)d_in[7];
  const float* b2  = (const float*)d_in[8];
  const float* s2  = (const float*)d_in[9];
  const float* w3  = (const float*)d_in[10];
  const float* b3  = (const float*)d_in[11];
  const float* s3  = (const float*)d_in[12];
  const float* wm0 = (const float*)d_in[13];
  const float* bm0 = (const float*)d_in[14];
  const float* wm1 = (const float*)d_in[15];
  const float* bm1 = (const float*)d_in[16];
  float* out = (float*)d_out;
  _Float16* wsh = (_Float16*)d_ws;

  int B = in_sizes[0] / 4096;
  // h scratch: d_ws if it fits, else overwrite the (already-consumed) x region
  size_t h_need = H_BYTE_OFF + (size_t)B * 4096 * 2;
  _Float16* hbuf = (ws_size >= h_need) ? (_Float16*)((char*)d_ws + H_BYTE_OFF)
                                       : (_Float16*)const_cast<float*>(x);

  prep_k_kernel<<<1, 256, 0, stream>>>(s0, s1, s2, s3, wsh + KT_OFF);
  prep_w_kernel<<<1298, 256, 0, stream>>>(w0, w1, w2, w3, wm0, wsh);
  gauss_phase<<<(B + 3) / 4, 256, 0, stream>>>(x, hbuf, b0, b1, b2, b3, wsh, B);
  dense_phase<<<(B + 15) / 16, 256, 0, stream>>>(hbuf, wsh, bm0, wm1, bm1, out, B);
}

// Round 4
// 514.802 us; speedup vs baseline: 1.4049x; 1.0480x over previous
//
#include <hip/hip_runtime.h>

// R4: two-phase with MFMA-fragment-ordered intermediate layouts.
// - h stored tiled [gaussBlock][kc=0..127][r=0..3][32] fp16: dense A-loads
//   become 4x256B segments (was 16x64B); line ownership per gauss block.
// - wm0 pre-tiled [kc=0..127][n=0..79][32] fp16: dense B-loads are 1KB
//   fully contiguous per instruction (was 16x64B gather).
// - dense K-loop unroll 2 for load prefetch.
// - single merged prep kernel (K~, small padded weights, wm0 tiling).

typedef _Float16 f16x8 __attribute__((ext_vector_type(8)));
typedef _Float16 f16x4 __attribute__((ext_vector_type(4)));
typedef float    f32x4 __attribute__((ext_vector_type(4)));

// ws layout (halves): [0] wm0 tiled [128][80][32]; K~ [4][64][64]; padded weights
#define KT_OFF    327680
#define W0P_OFF   344064               // [16][64], rows>=8 zero
#define W1P_OFF   345088               // [16][32], cols>=8 zero
#define W2P_OFF   345600               // [32][32], cols>=16 zero
#define W3P_OFF   346624               // [64][32]
#define H_BYTE_OFF 1048576             // h tiled buffer at +1MB

__global__ void prep_all(const float* __restrict__ s0, const float* __restrict__ s1,
                         const float* __restrict__ s2, const float* __restrict__ s3,
                         const float* __restrict__ w0, const float* __restrict__ w1,
                         const float* __restrict__ w2, const float* __restrict__ w3,
                         const float* __restrict__ wm0, _Float16* __restrict__ base) {
  int bid = blockIdx.x, tid = threadIdx.x;
  if (bid < 1280) {
    // wm0 fp32 [80][4096] -> fp16 tiled [kc][n][32]
    int idx = bid * 256 + tid;
    int kc = idx / 2560, rem = idx % 2560;
    int n = rem >> 5, o = rem & 31;
    base[idx] = (_Float16)wm0[n * 4096 + kc * 32 + o];
  } else if (bid == 1280) {
    // K~ : L1-normalized gaussian rows, fp16 [4][64][64]
    int li = tid >> 6, i = tid & 63;
    float sg = (li == 0) ? s0[0] : (li == 1) ? s1[0] : (li == 2) ? s2[0] : s3[0];
    float denom = 2.0f * sg * sg;
    float sum = 0.0f;
    for (int j = 0; j < 64; ++j) {
      float d = (float)(i - j);
      sum += expf(-(d * d) / denom);
    }
    float inv = 1.0f / fmaxf(sum, 1e-12f);
    for (int j = 0; j < 64; ++j) {
      float d = (float)(i - j);
      base[KT_OFF + (li * 64 + i) * 64 + j] = (_Float16)(expf(-(d * d) / denom) * inv);
    }
  } else {
    // small layer weights, zero-padded to MFMA tiles
    for (int r = tid; r < 4608; r += 256) {
      float v;
      if (r < 1024)      { int o = r >> 6, c = r & 63;             v = (o < 8)  ? w0[o * 64 + c] : 0.0f; }
      else if (r < 1536) { int q = r - 1024; int o = q >> 5, c = q & 31; v = (c < 8)  ? w1[o * 8 + c]  : 0.0f; }
      else if (r < 2560) { int q = r - 1536; int o = q >> 5, c = q & 31; v = (c < 16) ? w2[o * 16 + c] : 0.0f; }
      else               { int q = r - 2560; int o = q >> 5, c = q & 31; v = w3[o * 32 + c]; }
      base[W0P_OFF + r] = (_Float16)v;
    }
  }
}

__device__ __forceinline__ float leaky(float v) { return v > 0.0f ? v : 0.01f * v; }

// swizzled offset (halves) in an 8KB 64x64 fp16 buffer: 16B chunk j -> j ^ (row&7)
__device__ __forceinline__ int swz(int row, int c) {
  return row * 64 + ((((c >> 3) ^ (row & 7))) << 3) + (c & 7);
}

// stage A (in-place): xpT[o][h] over P from act_R[h][c] in P and w[o][c].
template<int NT, int KC, int KPAD>
__device__ __forceinline__ void stage_a(_Float16* __restrict__ P,
                                        const _Float16* __restrict__ wp, const float* bv,
                                        int lo, int hi) {
  f16x8 a[4][KC];
#pragma unroll
  for (int mt = 0; mt < 4; ++mt)
#pragma unroll
    for (int kc = 0; kc < KC; ++kc)
      a[mt][kc] = *(const f16x8*)(P + swz(mt * 16 + lo, kc * 32 + hi * 8));
  f16x8 wf[NT][KC];
#pragma unroll
  for (int nt = 0; nt < NT; ++nt)
#pragma unroll
    for (int kc = 0; kc < KC; ++kc)
      wf[nt][kc] = *(const f16x8*)(wp + (nt * 16 + lo) * KPAD + kc * 32 + hi * 8);
#pragma unroll
  for (int mt = 0; mt < 4; ++mt)
#pragma unroll
    for (int nt = 0; nt < NT; ++nt) {
      f32x4 acc = {0.0f, 0.0f, 0.0f, 0.0f};
#pragma unroll
      for (int kc = 0; kc < KC; ++kc)
        acc = __builtin_amdgcn_mfma_f32_16x16x32_f16(a[mt][kc], wf[nt][kc], acc, 0, 0, 0);
      f16x4 hv;
#pragma unroll
      for (int r = 0; r < 4; ++r) hv[r] = (_Float16)(acc[r] + bv[nt]);
      *(f16x4*)(P + swz(nt * 16 + lo, mt * 16 + hi * 4)) = hv;
    }
}

// stage B (in-place): act_R[i][o] = leaky(sum_j K~[i][j] * xpT[o][j])
template<int MT>
__device__ __forceinline__ void stage_b(_Float16* __restrict__ P,
                                        const _Float16* __restrict__ kmat, int lo, int hi) {
  f16x8 ax[MT][2];
#pragma unroll
  for (int ot = 0; ot < MT; ++ot)
#pragma unroll
    for (int kc = 0; kc < 2; ++kc)
      ax[ot][kc] = *(const f16x8*)(P + swz(ot * 16 + lo, kc * 32 + hi * 8));
  f16x8 kb[4][2];
#pragma unroll
  for (int nt = 0; nt < 4; ++nt)
#pragma unroll
    for (int kc = 0; kc < 2; ++kc)
      kb[nt][kc] = *(const f16x8*)(kmat + (nt * 16 + lo) * 64 + kc * 32 + hi * 8);
#pragma unroll
  for (int ot = 0; ot < MT; ++ot)
#pragma unroll
    for (int nt = 0; nt < 4; ++nt) {
      f32x4 acc = {0.0f, 0.0f, 0.0f, 0.0f};
#pragma unroll
      for (int kc = 0; kc < 2; ++kc)
        acc = __builtin_amdgcn_mfma_f32_16x16x32_f16(ax[ot][kc], kb[nt][kc], acc, 0, 0, 0);
      f16x4 hv;
#pragma unroll
      for (int r = 0; r < 4; ++r) hv[r] = (_Float16)leaky(acc[r]);
      *(f16x4*)(P + swz(nt * 16 + lo, ot * 16 + hi * 4)) = hv;
    }
}

__global__ __launch_bounds__(256, 4)
void gauss_phase(const float* __restrict__ x, _Float16* __restrict__ hout,
                 const float* __restrict__ bb0, const float* __restrict__ bb1,
                 const float* __restrict__ bb2, const float* __restrict__ bb3,
                 const _Float16* __restrict__ wsh, int B) {
  __shared__ _Float16 lds[4][4096];   // 32KB
  const int tid = threadIdx.x;
  const int wv = tid >> 6, lane = tid & 63;
  const int lo = lane & 15, hi = lane >> 4;
  const int smp = blockIdx.x * 4 + wv;
  if (smp >= B) return;               // whole-wave exit; no barriers in kernel
  _Float16* P = lds[wv];

  float bv0 = (lo < 8) ? bb0[lo] : 0.0f;
  float bv1 = bb1[lo];
  float bv2[2] = {bb2[lo], bb2[16 + lo]};
  float bv3[4] = {bb3[lo], bb3[16 + lo], bb3[32 + lo], bb3[48 + lo]};

  // x -> act_R fp16 swizzled (1KB contiguous per instruction)
  const float4* xv = (const float4*)(x + (size_t)smp * 4096);
#pragma unroll
  for (int t = 0; t < 16; ++t) {
    float4 v = xv[t * 64 + lane];
    f16x4 hv;
    hv[0] = (_Float16)v.x; hv[1] = (_Float16)v.y; hv[2] = (_Float16)v.z; hv[3] = (_Float16)v.w;
    *(f16x4*)(P + swz(t * 4 + hi, lo * 4)) = hv;
  }

  const _Float16* kt = wsh + KT_OFF;
  stage_a<1, 2, 64>(P, wsh + W0P_OFF, &bv0, lo, hi);
  stage_b<1>(P, kt + 0 * 4096, lo, hi);
  stage_a<1, 1, 32>(P, wsh + W1P_OFF, &bv1, lo, hi);
  stage_b<1>(P, kt + 1 * 4096, lo, hi);
  stage_a<2, 1, 32>(P, wsh + W2P_OFF, bv2, lo, hi);
  stage_b<2>(P, kt + 2 * 4096, lo, hi);
  stage_a<4, 1, 32>(P, wsh + W3P_OFF, bv3, lo, hi);
  stage_b<4>(P, kt + 3 * 4096, lo, hi);

  // h -> global TILED: [block][kc=0..127][r=wv][32], de-swizzled
  _Float16* g = hout + (size_t)blockIdx.x * 16384 + wv * 32 + (lane & 3) * 8;
#pragma unroll
  for (int t = 0; t < 8; ++t) {
    int c = t * 64 + lane;              // half-index/8 within sample
    int i = c >> 3, j = c & 7;
    f16x8 v = *(const f16x8*)(P + i * 64 + ((j ^ (i & 7)) << 3));
    *(f16x8*)(g + (size_t)(t * 16 + (lane >> 2)) * 128) = v;
  }
}

__global__ __launch_bounds__(256, 4)
void dense_phase(const _Float16* __restrict__ h, const _Float16* __restrict__ wm0t,
                 const float* __restrict__ bm0, const float* __restrict__ wm1,
                 const float* __restrict__ bm1, float* __restrict__ out, int B) {
  __shared__ float part[4][16][84];
  __shared__ float h1[16][84];
  const int tid = threadIdx.x;
  const int wv = tid >> 6, lane = tid & 63;
  const int lo = lane & 15, hi = lane >> 4;
  const int m0 = blockIdx.x * 16;

  int smp = m0 + lo;
  if (smp >= B) smp = B - 1;           // clamp; OOB outputs masked at store
  // A: h tiled [gb][kc][r][32] -> addr = gb*16384 + kc*128 + r*32 + hi*8
  const _Float16* abase = h + (size_t)(smp >> 2) * 16384 + (smp & 3) * 32 + hi * 8;
  // B: wm0 tiled [kc][n][32] -> addr = kc*2560 + n*32 + hi*8
  const _Float16* bbase = wm0t + (size_t)lo * 32 + hi * 8;

  f32x4 acc[5];
#pragma unroll
  for (int nt = 0; nt < 5; ++nt) { f32x4 z = {0.0f, 0.0f, 0.0f, 0.0f}; acc[nt] = z; }

#pragma unroll 2
  for (int it = 0; it < 32; ++it) {
    int kc = wv * 32 + it;
    f16x8 a = *(const f16x8*)(abase + (size_t)kc * 128);
    const _Float16* bp = bbase + (size_t)kc * 2560;
#pragma unroll
    for (int nt = 0; nt < 5; ++nt) {
      f16x8 b = *(const f16x8*)(bp + nt * 512);
      acc[nt] = __builtin_amdgcn_mfma_f32_16x16x32_f16(a, b, acc[nt], 0, 0, 0);
    }
  }
#pragma unroll
  for (int nt = 0; nt < 5; ++nt)
#pragma unroll
    for (int r = 0; r < 4; ++r)
      part[wv][hi * 4 + r][nt * 16 + lo] = acc[nt][r];
  __syncthreads();

  for (int e = tid; e < 16 * 80; e += 256) {
    int m = e / 80, n = e - m * 80;
    float v = bm0[n] + part[0][m][n] + part[1][m][n] + part[2][m][n] + part[3][m][n];
    h1[m][n] = leaky(v);
  }
  __syncthreads();

  for (int e = tid; e < 16 * 60; e += 256) {
    int m = e / 60, n = e - m * 60;
    float v = bm1[n];
    const float4* hr = (const float4*)&h1[m][0];
    const float4* wr = (const float4*)(wm1 + n * 80);
#pragma unroll
    for (int k2 = 0; k2 < 20; ++k2) {
      float4 hv = hr[k2], wv4 = wr[k2];
      v += hv.x * wv4.x + hv.y * wv4.y + hv.z * wv4.z + hv.w * wv4.w;
    }
    int s = m0 + m;
    if (s < B) out[(size_t)s * 60 + n] = leaky(v);
  }
}

extern "C" void kernel_launch(void* const* d_in, const int* in_sizes, int n_in,
                              void* d_out, int out_size, void* d_ws, size_t ws_size,
                              hipStream_t stream) {
  const float* x   = (const float*)d_in[0];
  const float* w0  = (const float*)d_in[1];
  const float* b0  = (const float*)d_in[2];
  const float* s0  = (const float*)d_in[3];
  const float* w1  = (const float*)d_in[4];
  const float* b1  = (const float*)d_in[5];
  const float* s1  = (const float*)d_in[6];
  const float* w2  = (const float*)d_in[7];
  const float* b2  = (const float*)d_in[8];
  const float* s2  = (const float*)d_in[9];
  const float* w3  = (const float*)d_in[10];
  const float* b3  = (const float*)d_in[11];
  const float* s3  = (const float*)d_in[12];
  const float* wm0 = (const float*)d_in[13];
  const float* bm0 = (const float*)d_in[14];
  const float* wm1 = (const float*)d_in[15];
  const float* bm1 = (const float*)d_in[16];
  float* out = (float*)d_out;
  _Float16* wsh = (_Float16*)d_ws;

  int B = in_sizes[0] / 4096;
  size_t h_need = H_BYTE_OFF + (size_t)B * 4096 * 2;
  _Float16* hbuf = (ws_size >= h_need) ? (_Float16*)((char*)d_ws + H_BYTE_OFF)
                                       : (_Float16*)const_cast<float*>(x);

  prep_all<<<1282, 256, 0, stream>>>(s0, s1, s2, s3, w0, w1, w2, w3, wm0, wsh);
  gauss_phase<<<(B + 3) / 4, 256, 0, stream>>>(x, hbuf, b0, b1, b2, b3, wsh, B);
  dense_phase<<<(B + 15) / 16, 256, 0, stream>>>(hbuf, wsh, bm0, wm1, bm1, out, B);
}